// Round 1
// baseline (115.574 us; speedup 1.0000x reference)
//
#include <hip/hip_runtime.h>

#define NQ 10
#define NG 4
#define QD 6
#define NBATCH 1024
// 2^NQ = 1024 amplitudes; 64 lanes * 16 amps/lane.
// Flat index i: bit p (from LSB) corresponds to wire q = NQ-1-p (wire 0 = MSB).
// i = lane*16 + j : bits 0..3 <- j (intra-lane), bits 4..9 <- lane (cross-lane).

__global__ __launch_bounds__(64) void qsim_kernel(
    const float* __restrict__ noise,     // (NBATCH, NQ)
    const float* __restrict__ qp,        // (NG, QD, NQ)
    float* __restrict__ out)             // (NBATCH, NG*NQ)
{
    const int circ = blockIdx.x;         // 0..4095
    const int b    = circ >> 2;          // batch index
    const int g    = circ & 3;           // generator index
    const int lane = threadIdx.x & 63;

    // ---- per-sample noise angles: c = cos(t/2), s = sin(t/2) ----
    float nc[NQ], ns[NQ];
#pragma unroll
    for (int q = 0; q < NQ; ++q) {
        float t = 0.5f * noise[b * NQ + q];
        nc[q] = __cosf(t);
        ns[q] = __sinf(t);
    }

    // ---- initial product state:  RY(t)RX(t)|0> = [c^2 - i s^2, cs - i cs] ----
    float ar[16], ai[16];
    // partial product over high bits 4..9 (wires 5..0), determined by lane
    float hr = 1.f, hi = 0.f;
#pragma unroll
    for (int p = 4; p <= 9; ++p) {
        const int q = NQ - 1 - p;
        const int bit = (lane >> (p - 4)) & 1;
        float cc = nc[q], ss = ns[q];
        float gr, gi;
        if (bit) { gr = cc * ss; gi = -gr; }
        else     { gr = cc * cc; gi = -ss * ss; }
        float tr = hr * gr - hi * gi;
        float ti = hr * gi + hi * gr;
        hr = tr; hi = ti;
    }
    // finish with low bits 0..3 (wires 9..6), determined by j (compile-time)
#pragma unroll
    for (int j = 0; j < 16; ++j) {
        float r = hr, im = hi;
#pragma unroll
        for (int p = 0; p < 4; ++p) {
            const int q = NQ - 1 - p;
            float cc = nc[q], ss = ns[q];
            float gr, gi;
            if ((j >> p) & 1) { gr = cc * ss; gi = -gr; }
            else              { gr = cc * cc; gi = -ss * ss; }
            float tr = r * gr - im * gi;
            float ti = r * gi + im * gr;
            r = tr; im = ti;
        }
        ar[j] = r; ai[j] = im;
    }

    // ---- CZ-chain diagonal sign per local element ----
    float czs[16];
#pragma unroll
    for (int j = 0; j < 16; ++j) {
        unsigned i = ((unsigned)lane << 4) | (unsigned)j;
        czs[j] = (__popc(i & (i >> 1)) & 1) ? -1.f : 1.f;
    }

    // ---- QD layers: RY(w[l][q]) on every wire, then CZ diagonal ----
    const float* w = qp + g * (QD * NQ);
#pragma unroll 1
    for (int l = 0; l < QD; ++l) {
#pragma unroll
        for (int q = 0; q < NQ; ++q) {
            float t = 0.5f * w[l * NQ + q];
            float c = __cosf(t), s = __sinf(t);
            const int p = NQ - 1 - q;   // bit position
            if (p < 4) {
                // intra-lane pairing (static register indices)
                const int m = 1 << p;
#pragma unroll
                for (int j = 0; j < 16; ++j) {
                    if ((j & m) == 0) {
                        const int k = j | m;
                        float a0 = ar[j], a1 = ar[k];
                        ar[j] = c * a0 - s * a1;
                        ar[k] = s * a0 + c * a1;
                        float b0 = ai[j], b1 = ai[k];
                        ai[j] = c * b0 - s * b1;
                        ai[k] = s * b0 + c * b1;
                    }
                }
            } else {
                // cross-lane pairing via shuffle
                const int lm = 1 << (p - 4);
                const float sgn = (lane & lm) ? s : -s;
#pragma unroll
                for (int j = 0; j < 16; ++j) {
                    float pa = __shfl_xor(ar[j], lm, 64);
                    float pb = __shfl_xor(ai[j], lm, 64);
                    ar[j] = c * ar[j] + sgn * pa;
                    ai[j] = c * ai[j] + sgn * pb;
                }
            }
        }
        // CZ diagonal (real +-1)
#pragma unroll
        for (int j = 0; j < 16; ++j) { ar[j] *= czs[j]; ai[j] *= czs[j]; }
    }

    // ---- expectations <X_q> = sum_i a_i a_{i^m} + b_i b_{i^m} ----
    float outval = 0.f;
#pragma unroll
    for (int q = 0; q < NQ; ++q) {
        const int p = NQ - 1 - q;
        float sum = 0.f;
        if (p < 4) {
            const int m = 1 << p;
#pragma unroll
            for (int j = 0; j < 16; ++j)
                sum += ar[j] * ar[j ^ m] + ai[j] * ai[j ^ m];
        } else {
            const int lm = 1 << (p - 4);
#pragma unroll
            for (int j = 0; j < 16; ++j) {
                sum += ar[j] * __shfl_xor(ar[j], lm, 64)
                     + ai[j] * __shfl_xor(ai[j], lm, 64);
            }
        }
        // wave-wide butterfly reduction (all lanes end with the total)
#pragma unroll
        for (int off = 32; off >= 1; off >>= 1)
            sum += __shfl_xor(sum, off, 64);
        if (lane == q) outval = sum;
    }

    if (lane < NQ)
        out[b * (NG * NQ) + g * NQ + lane] = outval;
}

extern "C" void kernel_launch(void* const* d_in, const int* in_sizes, int n_in,
                              void* d_out, int out_size, void* d_ws, size_t ws_size,
                              hipStream_t stream) {
    const float* noise = (const float*)d_in[0];   // (1024, 10) float32
    const float* qp    = (const float*)d_in[1];   // (4, 6, 10) float32
    float* out = (float*)d_out;                   // (1024, 40) float32

    const int nblocks = NBATCH * NG;              // one wave per (batch, gen)
    qsim_kernel<<<nblocks, 64, 0, stream>>>(noise, qp, out);
}

// Round 2
// 114.890 us; speedup vs baseline: 1.0060x; 1.0060x over previous
//
#include <hip/hip_runtime.h>

#define NQ 10
#define NG 4
#define QD 6
#define NBATCH 1024
#define WAVES_PER_BLOCK 4
// 2^NQ = 1024 amplitudes; 64 lanes * 16 amps/lane, one circuit per wave.
// Flat index i: bit p (from LSB) corresponds to wire q = NQ-1-p (wire 0 = MSB).
// i = lane*16 + j : bits 0..3 <- j (intra-lane), bits 4..9 <- lane (cross-lane).
// Block = 4 waves = 4 circuits; lifts the per-CU workgroup-slot occupancy cap
// that 1-wave blocks hit (31% measured occupancy in R1).

__global__ __launch_bounds__(64 * WAVES_PER_BLOCK) void qsim_kernel(
    const float* __restrict__ noise,     // (NBATCH, NQ)
    const float* __restrict__ qp,        // (NG, QD, NQ)
    float* __restrict__ out)             // (NBATCH, NG*NQ)
{
    const int wave = threadIdx.x >> 6;
    const int circ = blockIdx.x * WAVES_PER_BLOCK + wave;   // 0..4095
    const int b    = circ >> 2;          // batch index
    const int g    = circ & 3;           // generator index
    const int lane = threadIdx.x & 63;

    // ---- per-sample noise angles: c = cos(t/2), s = sin(t/2) ----
    float nc[NQ], ns[NQ];
#pragma unroll
    for (int q = 0; q < NQ; ++q) {
        float t = 0.5f * noise[b * NQ + q];
        __sincosf(t, &ns[q], &nc[q]);
    }

    // ---- initial product state:  RY(t)RX(t)|0> = [c^2 - i s^2, cs - i cs] ----
    float ar[16], ai[16];
    // partial product over high bits 4..9 (wires 5..0), determined by lane
    float hr = 1.f, hi = 0.f;
#pragma unroll
    for (int p = 4; p <= 9; ++p) {
        const int q = NQ - 1 - p;
        const int bit = (lane >> (p - 4)) & 1;
        float cc = nc[q], ss = ns[q];
        float gr, gi;
        if (bit) { gr = cc * ss; gi = -gr; }
        else     { gr = cc * cc; gi = -ss * ss; }
        float tr = hr * gr - hi * gi;
        float ti = hr * gi + hi * gr;
        hr = tr; hi = ti;
    }
    // finish with low bits 0..3 (wires 9..6), determined by j (compile-time)
#pragma unroll
    for (int j = 0; j < 16; ++j) {
        float r = hr, im = hi;
#pragma unroll
        for (int p = 0; p < 4; ++p) {
            const int q = NQ - 1 - p;
            float cc = nc[q], ss = ns[q];
            float gr, gi;
            if ((j >> p) & 1) { gr = cc * ss; gi = -gr; }
            else              { gr = cc * cc; gi = -ss * ss; }
            float tr = r * gr - im * gi;
            float ti = r * gi + im * gr;
            r = tr; im = ti;
        }
        ar[j] = r; ai[j] = im;
    }

    // ---- CZ-chain diagonal sign per local element ----
    float czs[16];
#pragma unroll
    for (int j = 0; j < 16; ++j) {
        unsigned i = ((unsigned)lane << 4) | (unsigned)j;
        czs[j] = (__popc(i & (i >> 1)) & 1) ? -1.f : 1.f;
    }

    // ---- QD layers: RY(w[l][q]) on every wire, then CZ diagonal ----
    const float* w = qp + g * (QD * NQ);
#pragma unroll 1
    for (int l = 0; l < QD; ++l) {
#pragma unroll
        for (int q = 0; q < NQ; ++q) {
            float t = 0.5f * w[l * NQ + q];
            float c, s;
            __sincosf(t, &s, &c);
            const int p = NQ - 1 - q;   // bit position
            if (p < 4) {
                // intra-lane pairing (static register indices)
                const int m = 1 << p;
#pragma unroll
                for (int j = 0; j < 16; ++j) {
                    if ((j & m) == 0) {
                        const int k = j | m;
                        float a0 = ar[j], a1 = ar[k];
                        ar[j] = c * a0 - s * a1;
                        ar[k] = s * a0 + c * a1;
                        float b0 = ai[j], b1 = ai[k];
                        ai[j] = c * b0 - s * b1;
                        ai[k] = s * b0 + c * b1;
                    }
                }
            } else {
                // cross-lane pairing via shuffle
                const int lm = 1 << (p - 4);
                const float sgn = (lane & lm) ? s : -s;
#pragma unroll
                for (int j = 0; j < 16; ++j) {
                    float pa = __shfl_xor(ar[j], lm, 64);
                    float pb = __shfl_xor(ai[j], lm, 64);
                    ar[j] = c * ar[j] + sgn * pa;
                    ai[j] = c * ai[j] + sgn * pb;
                }
            }
        }
        // CZ diagonal (real +-1)
#pragma unroll
        for (int j = 0; j < 16; ++j) { ar[j] *= czs[j]; ai[j] *= czs[j]; }
    }

    // ---- expectations <X_q> = sum_i a_i a_{i^m} + b_i b_{i^m} ----
    float outval = 0.f;
#pragma unroll
    for (int q = 0; q < NQ; ++q) {
        const int p = NQ - 1 - q;
        float sum = 0.f;
        if (p < 4) {
            const int m = 1 << p;
#pragma unroll
            for (int j = 0; j < 16; ++j)
                sum += ar[j] * ar[j ^ m] + ai[j] * ai[j ^ m];
        } else {
            const int lm = 1 << (p - 4);
#pragma unroll
            for (int j = 0; j < 16; ++j) {
                sum += ar[j] * __shfl_xor(ar[j], lm, 64)
                     + ai[j] * __shfl_xor(ai[j], lm, 64);
            }
        }
        // wave-wide butterfly reduction (all lanes end with the total)
#pragma unroll
        for (int off = 32; off >= 1; off >>= 1)
            sum += __shfl_xor(sum, off, 64);
        if (lane == q) outval = sum;
    }

    if (lane < NQ)
        out[b * (NG * NQ) + g * NQ + lane] = outval;
}

extern "C" void kernel_launch(void* const* d_in, const int* in_sizes, int n_in,
                              void* d_out, int out_size, void* d_ws, size_t ws_size,
                              hipStream_t stream) {
    const float* noise = (const float*)d_in[0];   // (1024, 10) float32
    const float* qp    = (const float*)d_in[1];   // (4, 6, 10) float32
    float* out = (float*)d_out;                   // (1024, 40) float32

    const int nblocks = (NBATCH * NG) / WAVES_PER_BLOCK; // 4 circuits per block
    qsim_kernel<<<nblocks, 64 * WAVES_PER_BLOCK, 0, stream>>>(noise, qp, out);
}

// Round 3
// 99.606 us; speedup vs baseline: 1.1603x; 1.1534x over previous
//
#include <hip/hip_runtime.h>

#define NQ 10
#define NG 4
#define QD 6
#define NBATCH 1024
#define WPB 4   // waves per block; block handles 4 batch samples of ONE generator

// 2^10 = 1024 amps; 64 lanes x 16 amps/lane, one circuit per wave.
// Flat index i: bit p (LSB) <-> wire q = 9-p (wire 0 = MSB, PennyLane order).
// i = lane*16 + j : bits 0..3 <- j (intra-lane), bits 4..9 <- lane (cross-lane).
// R3: cross-lane partner fetch for lane-xor masks 1,2,4,8 moved from the LDS
// pipe (ds_swizzle) to the VALU pipe (DPP): xor1/xor2 = quad_perm, xor4 =
// half_mirror o quad_xor3, xor8 = mirror o half_mirror. xor16/32 stay shfl.
// Butterfly reduction replaced by DPP row_shr/row_bcast reduce (VALU only).

template<int CTRL, int RM, int BM, bool BC>
__device__ __forceinline__ float dppmov(float x) {
    return __int_as_float(__builtin_amdgcn_update_dpp(
        0, __float_as_int(x), CTRL, RM, BM, BC));
}

__device__ __forceinline__ float pxor1 (float x){ return dppmov<0xB1,0xF,0xF,false>(x); }  // quad_perm {1,0,3,2}
__device__ __forceinline__ float pxor2 (float x){ return dppmov<0x4E,0xF,0xF,false>(x); }  // quad_perm {2,3,0,1}
__device__ __forceinline__ float pxor4 (float x){                                          // xor7 then xor3 = xor4
    return dppmov<0x1B,0xF,0xF,false>(dppmov<0x141,0xF,0xF,false>(x));
}
__device__ __forceinline__ float pxor8 (float x){                                          // xor15 then xor7 = xor8
    return dppmov<0x141,0xF,0xF,false>(dppmov<0x140,0xF,0xF,false>(x));
}
__device__ __forceinline__ float pxor16(float x){ return __shfl_xor(x, 16, 64); }
__device__ __forceinline__ float pxor32(float x){ return __shfl_xor(x, 32, 64); }

struct PX1  { static __device__ __forceinline__ float f(float x){ return pxor1(x); } };
struct PX2  { static __device__ __forceinline__ float f(float x){ return pxor2(x); } };
struct PX4  { static __device__ __forceinline__ float f(float x){ return pxor4(x); } };
struct PX8  { static __device__ __forceinline__ float f(float x){ return pxor8(x); } };
struct PX16 { static __device__ __forceinline__ float f(float x){ return pxor16(x); } };
struct PX32 { static __device__ __forceinline__ float f(float x){ return pxor32(x); } };

// wave-wide sum, result broadcast from lane 63 via readlane (uniform)
__device__ __forceinline__ float wave_reduce(float x) {
    x += dppmov<0x111,0xF,0xF,true >(x);   // row_shr:1
    x += dppmov<0x112,0xF,0xF,true >(x);   // row_shr:2
    x += dppmov<0x114,0xF,0xF,true >(x);   // row_shr:4
    x += dppmov<0x118,0xF,0xF,true >(x);   // row_shr:8  -> lane15 of each row = row sum
    x += dppmov<0x142,0xA,0xF,false>(x);   // row_bcast15 into rows 1,3
    x += dppmov<0x143,0xC,0xF,false>(x);   // row_bcast31 into rows 2,3 -> lane63 = total
    return __int_as_float(__builtin_amdgcn_readlane(__float_as_int(x), 63));
}

template<class PF, int LM>
__device__ __forceinline__ void cross_rot(float (&ar)[16], float (&ai)[16],
                                          float c, float s, int lane) {
    const float sgn = (lane & LM) ? s : -s;
#pragma unroll
    for (int j = 0; j < 16; ++j) {
        float pa = PF::f(ar[j]);
        float pb = PF::f(ai[j]);
        ar[j] = c * ar[j] + sgn * pa;
        ai[j] = c * ai[j] + sgn * pb;
    }
}

template<int M>
__device__ __forceinline__ void intra_rot(float (&ar)[16], float (&ai)[16],
                                          float c, float s) {
#pragma unroll
    for (int j = 0; j < 16; ++j) {
        if ((j & M) == 0) {
            const int k = j | M;
            float a0 = ar[j], a1 = ar[k];
            ar[j] = c * a0 - s * a1;
            ar[k] = s * a0 + c * a1;
            float b0 = ai[j], b1 = ai[k];
            ai[j] = c * b0 - s * b1;
            ai[k] = s * b0 + c * b1;
        }
    }
}

template<class PF>
__device__ __forceinline__ float cross_exp(const float (&ar)[16], const float (&ai)[16]) {
    float sum = 0.f;
#pragma unroll
    for (int j = 0; j < 16; ++j)
        sum += ar[j] * PF::f(ar[j]) + ai[j] * PF::f(ai[j]);
    return sum;
}

template<int M>
__device__ __forceinline__ float intra_exp(const float (&ar)[16], const float (&ai)[16]) {
    float sum = 0.f;
#pragma unroll
    for (int j = 0; j < 16; ++j)
        sum += ar[j] * ar[j ^ M] + ai[j] * ai[j ^ M];
    return sum;
}

__global__ __launch_bounds__(64 * WPB) void qsim_kernel(
    const float* __restrict__ noise,     // (NBATCH, NQ)
    const float* __restrict__ qp,        // (NG, QD, NQ)
    float* __restrict__ out)             // (NBATCH, NG*NQ)
{
    const int wave = threadIdx.x >> 6;
    const int lane = threadIdx.x & 63;
    const int g    = blockIdx.x & 3;                  // block-uniform -> s_load weights
    const int b    = (blockIdx.x >> 2) * WPB + wave;  // batch sample per wave

    // ---- per-sample noise angles ----
    float nc[NQ], ns[NQ];
#pragma unroll
    for (int q = 0; q < NQ; ++q) {
        float t = 0.5f * noise[b * NQ + q];
        __sincosf(t, &ns[q], &nc[q]);
    }

    // ---- initial product state: RX(t)RY(t)|0> = [c^2 - i s^2, cs - i cs] ----
    float ar[16], ai[16];
    float hr = 1.f, hi = 0.f;
#pragma unroll
    for (int p = 4; p <= 9; ++p) {
        const int q = NQ - 1 - p;
        const int bit = (lane >> (p - 4)) & 1;
        float cc = nc[q], ss = ns[q];
        float gr, gi;
        if (bit) { gr = cc * ss; gi = -gr; }
        else     { gr = cc * cc; gi = -ss * ss; }
        float tr = hr * gr - hi * gi;
        float ti = hr * gi + hi * gr;
        hr = tr; hi = ti;
    }
#pragma unroll
    for (int j = 0; j < 16; ++j) {
        float r = hr, im = hi;
#pragma unroll
        for (int p = 0; p < 4; ++p) {
            const int q = NQ - 1 - p;
            float cc = nc[q], ss = ns[q];
            float gr, gi;
            if ((j >> p) & 1) { gr = cc * ss; gi = -gr; }
            else              { gr = cc * cc; gi = -ss * ss; }
            float tr = r * gr - im * gi;
            float ti = r * gi + im * gr;
            r = tr; im = ti;
        }
        ar[j] = r; ai[j] = im;
    }

    // ---- CZ-chain diagonal sign per local element ----
    float czs[16];
#pragma unroll
    for (int j = 0; j < 16; ++j) {
        unsigned i = ((unsigned)lane << 4) | (unsigned)j;
        czs[j] = (__popc(i & (i >> 1)) & 1) ? -1.f : 1.f;
    }

    // ---- QD layers ----
    const float* w = qp + g * (QD * NQ);
#pragma unroll 1
    for (int l = 0; l < QD; ++l) {
        float c[NQ], sn[NQ];
#pragma unroll
        for (int q = 0; q < NQ; ++q)
            __sincosf(0.5f * w[l * NQ + q], &sn[q], &c[q]);

        cross_rot<PX32,32>(ar, ai, c[0], sn[0], lane);  // q=0, bit 9
        cross_rot<PX16,16>(ar, ai, c[1], sn[1], lane);  // q=1, bit 8
        cross_rot<PX8 , 8>(ar, ai, c[2], sn[2], lane);  // q=2, bit 7
        cross_rot<PX4 , 4>(ar, ai, c[3], sn[3], lane);  // q=3, bit 6
        cross_rot<PX2 , 2>(ar, ai, c[4], sn[4], lane);  // q=4, bit 5
        cross_rot<PX1 , 1>(ar, ai, c[5], sn[5], lane);  // q=5, bit 4
        intra_rot<8>(ar, ai, c[6], sn[6]);              // q=6, bit 3
        intra_rot<4>(ar, ai, c[7], sn[7]);              // q=7, bit 2
        intra_rot<2>(ar, ai, c[8], sn[8]);              // q=8, bit 1
        intra_rot<1>(ar, ai, c[9], sn[9]);              // q=9, bit 0

#pragma unroll
        for (int j = 0; j < 16; ++j) { ar[j] *= czs[j]; ai[j] *= czs[j]; }
    }

    // ---- expectations <X_q> ----
    float outval = 0.f;
    {
        float s0 = wave_reduce(cross_exp<PX32>(ar, ai)); outval = (lane == 0) ? s0 : outval;
        float s1 = wave_reduce(cross_exp<PX16>(ar, ai)); outval = (lane == 1) ? s1 : outval;
        float s2 = wave_reduce(cross_exp<PX8 >(ar, ai)); outval = (lane == 2) ? s2 : outval;
        float s3 = wave_reduce(cross_exp<PX4 >(ar, ai)); outval = (lane == 3) ? s3 : outval;
        float s4 = wave_reduce(cross_exp<PX2 >(ar, ai)); outval = (lane == 4) ? s4 : outval;
        float s5 = wave_reduce(cross_exp<PX1 >(ar, ai)); outval = (lane == 5) ? s5 : outval;
        float s6 = wave_reduce(intra_exp<8>(ar, ai));    outval = (lane == 6) ? s6 : outval;
        float s7 = wave_reduce(intra_exp<4>(ar, ai));    outval = (lane == 7) ? s7 : outval;
        float s8 = wave_reduce(intra_exp<2>(ar, ai));    outval = (lane == 8) ? s8 : outval;
        float s9 = wave_reduce(intra_exp<1>(ar, ai));    outval = (lane == 9) ? s9 : outval;
    }

    if (lane < NQ)
        out[b * (NG * NQ) + g * NQ + lane] = outval;
}

extern "C" void kernel_launch(void* const* d_in, const int* in_sizes, int n_in,
                              void* d_out, int out_size, void* d_ws, size_t ws_size,
                              hipStream_t stream) {
    const float* noise = (const float*)d_in[0];   // (1024, 10) float32
    const float* qp    = (const float*)d_in[1];   // (4, 6, 10) float32
    float* out = (float*)d_out;                   // (1024, 40) float32

    const int nblocks = (NBATCH * NG) / WPB;      // 1024 blocks x 4 waves
    qsim_kernel<<<nblocks, 64 * WPB, 0, stream>>>(noise, qp, out);
}

// Round 4
// 97.110 us; speedup vs baseline: 1.1901x; 1.0257x over previous
//
#include <hip/hip_runtime.h>

#define NQ 10
#define NG 4
#define QD 6
#define NBATCH 1024
#define WPB 4   // waves per block; block handles 4 batch samples of ONE generator

// 2^10 = 1024 amps; 64 lanes x 16 amps/lane, one circuit per wave.
// Flat index i: bit p (LSB) <-> wire q = 9-p (wire 0 = MSB, PennyLane order).
// i = lane*16 + j : bits 0..3 <- j (intra-lane), bits 4..9 <- lane (cross-lane).
// R4: state packed as v2f (re,im) so all rotation/CZ/expectation arithmetic
// lowers to packed fp32 VOP3P (v_pk_fma_f32 etc., gfx950 FeaturePackedFP32Ops)
// -> ~2x VALU instruction density. Partner fetch: xor1/2 = 1 DPP mov per
// component, xor4/8 = 2 DPP movs, xor16 = ds_swizzle 0x401F, xor32 = shfl.

typedef float v2f __attribute__((ext_vector_type(2)));

template<int CTRL, int RM, int BM, bool BC>
__device__ __forceinline__ float dppmov(float x) {
    return __int_as_float(__builtin_amdgcn_update_dpp(
        0, __float_as_int(x), CTRL, RM, BM, BC));
}

template<int CTRL>
__device__ __forceinline__ v2f dpp2(v2f x) {
    v2f r;
    r.x = dppmov<CTRL,0xF,0xF,false>(x.x);
    r.y = dppmov<CTRL,0xF,0xF,false>(x.y);
    return r;
}

__device__ __forceinline__ float swz16(float x) {
    return __int_as_float(__builtin_amdgcn_ds_swizzle(__float_as_int(x), 0x401F));
}

struct PX1  { static __device__ __forceinline__ v2f f(v2f x){ return dpp2<0xB1>(x); } };          // quad_perm {1,0,3,2}
struct PX2  { static __device__ __forceinline__ v2f f(v2f x){ return dpp2<0x4E>(x); } };          // quad_perm {2,3,0,1}
struct PX4  { static __device__ __forceinline__ v2f f(v2f x){ return dpp2<0x1B>(dpp2<0x141>(x)); } }; // xor7 o xor3
struct PX8  { static __device__ __forceinline__ v2f f(v2f x){ return dpp2<0x141>(dpp2<0x140>(x)); } }; // xor7 o xor15
struct PX16 { static __device__ __forceinline__ v2f f(v2f x){ v2f r; r.x = swz16(x.x); r.y = swz16(x.y); return r; } };
struct PX32 { static __device__ __forceinline__ v2f f(v2f x){ v2f r; r.x = __shfl_xor(x.x, 32, 64); r.y = __shfl_xor(x.y, 32, 64); return r; } };

// wave-wide sum, result broadcast from lane 63 via readlane (uniform)
__device__ __forceinline__ float wave_reduce(float x) {
    x += dppmov<0x111,0xF,0xF,true >(x);   // row_shr:1
    x += dppmov<0x112,0xF,0xF,true >(x);   // row_shr:2
    x += dppmov<0x114,0xF,0xF,true >(x);   // row_shr:4
    x += dppmov<0x118,0xF,0xF,true >(x);   // row_shr:8  -> lane15 of each row = row sum
    x += dppmov<0x142,0xA,0xF,false>(x);   // row_bcast15 into rows 1,3
    x += dppmov<0x143,0xC,0xF,false>(x);   // row_bcast31 into rows 2,3 -> lane63 = total
    return __int_as_float(__builtin_amdgcn_readlane(__float_as_int(x), 63));
}

__device__ __forceinline__ v2f cmul(v2f a, v2f b) {
    v2f r;
    r.x = a.x * b.x - a.y * b.y;
    r.y = a.x * b.y + a.y * b.x;
    return r;
}

template<class PF, int LM>
__device__ __forceinline__ void cross_rot(v2f (&s)[16], float c, float sn, int lane) {
    const float sgn = (lane & LM) ? sn : -sn;
#pragma unroll
    for (int j = 0; j < 16; ++j) {
        v2f p = PF::f(s[j]);
        s[j] = c * s[j] + sgn * p;          // v_pk_mul + v_pk_fma
    }
}

template<int M>
__device__ __forceinline__ void intra_rot(v2f (&s)[16], float c, float sn) {
#pragma unroll
    for (int j = 0; j < 16; ++j) {
        if ((j & M) == 0) {
            const int k = j | M;
            v2f v0 = s[j], v1 = s[k];
            s[j] = c * v0 - sn * v1;        // 2 pk instrs
            s[k] = sn * v0 + c * v1;        // 2 pk instrs
        }
    }
}

template<class PF>
__device__ __forceinline__ float cross_exp(const v2f (&s)[16]) {
    v2f acc = {0.f, 0.f};
#pragma unroll
    for (int j = 0; j < 16; ++j) {
        v2f p = PF::f(s[j]);
        acc += s[j] * p;                    // v_pk_fma
    }
    return acc.x + acc.y;
}

template<int M>
__device__ __forceinline__ float intra_exp(const v2f (&s)[16]) {
    v2f acc = {0.f, 0.f};
#pragma unroll
    for (int j = 0; j < 16; ++j)
        acc += s[j] * s[j ^ M];             // v_pk_fma
    return acc.x + acc.y;
}

__global__ __launch_bounds__(64 * WPB) void qsim_kernel(
    const float* __restrict__ noise,     // (NBATCH, NQ)
    const float* __restrict__ qp,        // (NG, QD, NQ)
    float* __restrict__ out)             // (NBATCH, NG*NQ)
{
    const int wave = threadIdx.x >> 6;
    const int lane = threadIdx.x & 63;
    const int g    = blockIdx.x & 3;                  // block-uniform -> s_load weights
    const int b    = (blockIdx.x >> 2) * WPB + wave;  // batch sample per wave

    // ---- per-sample noise angles ----
    float nc[NQ], ns[NQ];
#pragma unroll
    for (int q = 0; q < NQ; ++q) {
        float t = 0.5f * noise[b * NQ + q];
        __sincosf(t, &ns[q], &nc[q]);
    }

    // ---- initial product state: per-qubit factor RX(t)RY(t)|0>:
    //      bit=0 -> (c^2, -s^2)   bit=1 -> (cs, -cs)
    auto fac = [&](int q, int bit) -> v2f {
        float cc = nc[q], ss = ns[q];
        v2f r;
        if (bit) { r.x = cc * ss; r.y = -r.x; }
        else     { r.x = cc * cc; r.y = -ss * ss; }
        return r;
    };

    // lane-determined product over bits 4..9 (wires 5..0)
    v2f h = {1.f, 0.f};
#pragma unroll
    for (int p = 4; p <= 9; ++p)
        h = cmul(h, fac(NQ - 1 - p, (lane >> (p - 4)) & 1));

    // factor tree over low bits: t01 covers bits 0,1 (wires 9,8), t23 bits 2,3
    v2f s[16];
    {
        v2f t01[4], t23[4];
#pragma unroll
        for (int a = 0; a < 4; ++a) {
            t01[a] = cmul(fac(9, a & 1), fac(8, (a >> 1) & 1));
            t23[a] = cmul(fac(7, a & 1), fac(6, (a >> 1) & 1));
        }
        v2f pre[4];
#pragma unroll
        for (int a = 0; a < 4; ++a) pre[a] = cmul(h, t01[a]);
#pragma unroll
        for (int j = 0; j < 16; ++j) s[j] = cmul(pre[j & 3], t23[j >> 2]);
    }

    // ---- CZ-chain diagonal sign per local element ----
    float czs[16];
#pragma unroll
    for (int j = 0; j < 16; ++j) {
        unsigned i = ((unsigned)lane << 4) | (unsigned)j;
        czs[j] = (__popc(i & (i >> 1)) & 1) ? -1.f : 1.f;
    }

    // ---- QD layers ----
    const float* w = qp + g * (QD * NQ);
#pragma unroll 1
    for (int l = 0; l < QD; ++l) {
        float c[NQ], sn[NQ];
#pragma unroll
        for (int q = 0; q < NQ; ++q)
            __sincosf(0.5f * w[l * NQ + q], &sn[q], &c[q]);

        cross_rot<PX32,32>(s, c[0], sn[0], lane);  // q=0, bit 9
        cross_rot<PX16,16>(s, c[1], sn[1], lane);  // q=1, bit 8
        cross_rot<PX8 , 8>(s, c[2], sn[2], lane);  // q=2, bit 7
        cross_rot<PX4 , 4>(s, c[3], sn[3], lane);  // q=3, bit 6
        cross_rot<PX2 , 2>(s, c[4], sn[4], lane);  // q=4, bit 5
        cross_rot<PX1 , 1>(s, c[5], sn[5], lane);  // q=5, bit 4
        intra_rot<8>(s, c[6], sn[6]);              // q=6, bit 3
        intra_rot<4>(s, c[7], sn[7]);              // q=7, bit 2
        intra_rot<2>(s, c[8], sn[8]);              // q=8, bit 1
        intra_rot<1>(s, c[9], sn[9]);              // q=9, bit 0

#pragma unroll
        for (int j = 0; j < 16; ++j) s[j] *= czs[j];   // v_pk_mul
    }

    // ---- expectations <X_q> ----
    float outval = 0.f;
    {
        float s0 = wave_reduce(cross_exp<PX32>(s)); outval = (lane == 0) ? s0 : outval;
        float s1 = wave_reduce(cross_exp<PX16>(s)); outval = (lane == 1) ? s1 : outval;
        float s2 = wave_reduce(cross_exp<PX8 >(s)); outval = (lane == 2) ? s2 : outval;
        float s3 = wave_reduce(cross_exp<PX4 >(s)); outval = (lane == 3) ? s3 : outval;
        float s4 = wave_reduce(cross_exp<PX2 >(s)); outval = (lane == 4) ? s4 : outval;
        float s5 = wave_reduce(cross_exp<PX1 >(s)); outval = (lane == 5) ? s5 : outval;
        float s6 = wave_reduce(intra_exp<8>(s));    outval = (lane == 6) ? s6 : outval;
        float s7 = wave_reduce(intra_exp<4>(s));    outval = (lane == 7) ? s7 : outval;
        float s8 = wave_reduce(intra_exp<2>(s));    outval = (lane == 8) ? s8 : outval;
        float s9 = wave_reduce(intra_exp<1>(s));    outval = (lane == 9) ? s9 : outval;
    }

    if (lane < NQ)
        out[b * (NG * NQ) + g * NQ + lane] = outval;
}

extern "C" void kernel_launch(void* const* d_in, const int* in_sizes, int n_in,
                              void* d_out, int out_size, void* d_ws, size_t ws_size,
                              hipStream_t stream) {
    const float* noise = (const float*)d_in[0];   // (1024, 10) float32
    const float* qp    = (const float*)d_in[1];   // (4, 6, 10) float32
    float* out = (float*)d_out;                   // (1024, 40) float32

    const int nblocks = (NBATCH * NG) / WPB;      // 1024 blocks x 4 waves
    qsim_kernel<<<nblocks, 64 * WPB, 0, stream>>>(noise, qp, out);
}

// Round 6
// 96.298 us; speedup vs baseline: 1.2002x; 1.0084x over previous
//
#include <hip/hip_runtime.h>

#define NQ 10
#define NG 4
#define QD 6
#define NBATCH 1024
#define WPB 4   // waves per block; block = 4 batch samples of ONE generator

// 2^10 = 1024 amps; 64 lanes x 16 amps/lane, one circuit per wave.
// Flat index i: bit p (LSB) <-> wire q = 9-p (wire 0 = MSB, PennyLane order).
// i = lane*16 + j : bits 0..3 <- j (intra-lane), bits 4..9 <- lane bits 0..5.
// R6: R5 structure, but permlane swaps via the gfx950 BUILTINS
// (__builtin_amdgcn_permlane{16,32}_swap) so the compiler handles the
// VALU->permlane hazard that broke R5's raw-asm version. Zero LDS-pipe ops.

typedef float v2f __attribute__((ext_vector_type(2)));
typedef unsigned u2v __attribute__((ext_vector_type(2)));

// ---------- DPP helpers ----------
template<int CTRL>
__device__ __forceinline__ float dpp1(float x) {
    return __int_as_float(__builtin_amdgcn_update_dpp(
        0, __float_as_int(x), CTRL, 0xF, 0xF, false));
}
template<int CTRL>
__device__ __forceinline__ v2f dpp2(v2f x) {
    v2f r; r.x = dpp1<CTRL>(x.x); r.y = dpp1<CTRL>(x.y); return r;
}
// xor1 = quad_perm{1,0,3,2}=0xB1; xor2 = quad_perm{2,3,0,1}=0x4E;
// xor4 = row_half_mirror(^7)=0x141 then quad_perm{3,2,1,0}(^3)=0x1B;
// xor8 = row_ror:8 = 0x128 (rotate-by-8 mod 16 == xor 8).

struct FX1 { static __device__ __forceinline__ v2f f(v2f x){ return dpp2<0xB1>(x); } };
struct FX2 { static __device__ __forceinline__ v2f f(v2f x){ return dpp2<0x4E>(x); } };
struct FX4 { static __device__ __forceinline__ v2f f(v2f x){ return dpp2<0x1B>(dpp2<0x141>(x)); } };
struct FX8 { static __device__ __forceinline__ v2f f(v2f x){ return dpp2<0x128>(x); } };
// fallback fetches (only used if permlane-swap builtins are unavailable)
struct FX16 {
    static __device__ __forceinline__ v2f f(v2f x){
        v2f r;
        r.x = __int_as_float(__builtin_amdgcn_ds_swizzle(__float_as_int(x.x), 0x401F));
        r.y = __int_as_float(__builtin_amdgcn_ds_swizzle(__float_as_int(x.y), 0x401F));
        return r;
    }
};
struct FX32 {
    static __device__ __forceinline__ v2f f(v2f x){
        v2f r; r.x = __shfl_xor(x.x, 32, 64); r.y = __shfl_xor(x.y, 32, 64); return r;
    }
};

__device__ __forceinline__ float rlane(float v, int idx) {
    return __int_as_float(__builtin_amdgcn_readlane(__float_as_int(v), idx));
}

// ---------- gfx950 permlane swap transposes (VALU pipe, hazard-safe builtins) ----------
#if __has_builtin(__builtin_amdgcn_permlane32_swap) && __has_builtin(__builtin_amdgcn_permlane16_swap)
#define HAVE_SWAP 1
// permlane32_swap: A[lanes 32..63] <-> B[lanes 0..31]
// => transpose lane-bit5 <-> reg-bit3 for pair (s[j], s[j|8])
__device__ __forceinline__ void tr_b5b3(v2f (&s)[16]) {
#pragma unroll
    for (int j = 0; j < 8; ++j) {
        {
            u2v r = __builtin_amdgcn_permlane32_swap(
                __float_as_uint(s[j].x), __float_as_uint(s[j + 8].x), false, false);
            s[j].x = __uint_as_float(r.x); s[j + 8].x = __uint_as_float(r.y);
        }
        {
            u2v r = __builtin_amdgcn_permlane32_swap(
                __float_as_uint(s[j].y), __float_as_uint(s[j + 8].y), false, false);
            s[j].y = __uint_as_float(r.x); s[j + 8].y = __uint_as_float(r.y);
        }
    }
}
// permlane16_swap: A rows 1,3 (lanes 16-31,48-63) <-> B rows 0,2 (lanes 0-15,32-47)
// => transpose lane-bit4 <-> reg-bit2 for pair (s[j], s[j|4])
__device__ __forceinline__ void tr_b4b2(v2f (&s)[16]) {
#pragma unroll
    for (int jj = 0; jj < 8; ++jj) {
        const int j = (jj & 3) | ((jj >> 2) << 3);   // 0,1,2,3,8,9,10,11
        {
            u2v r = __builtin_amdgcn_permlane16_swap(
                __float_as_uint(s[j].x), __float_as_uint(s[j + 4].x), false, false);
            s[j].x = __uint_as_float(r.x); s[j + 4].x = __uint_as_float(r.y);
        }
        {
            u2v r = __builtin_amdgcn_permlane16_swap(
                __float_as_uint(s[j].y), __float_as_uint(s[j + 4].y), false, false);
            s[j].y = __uint_as_float(r.x); s[j + 4].y = __uint_as_float(r.y);
        }
    }
}
#else
#define HAVE_SWAP 0
#endif

// wave-wide sum, broadcast from lane 63 (validated R3/R4)
__device__ __forceinline__ float wave_reduce(float x) {
    x += __int_as_float(__builtin_amdgcn_update_dpp(0, __float_as_int(x), 0x111, 0xF, 0xF, true));
    x += __int_as_float(__builtin_amdgcn_update_dpp(0, __float_as_int(x), 0x112, 0xF, 0xF, true));
    x += __int_as_float(__builtin_amdgcn_update_dpp(0, __float_as_int(x), 0x114, 0xF, 0xF, true));
    x += __int_as_float(__builtin_amdgcn_update_dpp(0, __float_as_int(x), 0x118, 0xF, 0xF, true));
    x += __int_as_float(__builtin_amdgcn_update_dpp(0, __float_as_int(x), 0x142, 0xA, 0xF, false));
    x += __int_as_float(__builtin_amdgcn_update_dpp(0, __float_as_int(x), 0x143, 0xC, 0xF, false));
    return __int_as_float(__builtin_amdgcn_readlane(__float_as_int(x), 63));
}

__device__ __forceinline__ v2f cmul(v2f a, v2f b) {
    v2f r;
    r.x = a.x * b.x - a.y * b.y;
    r.y = a.x * b.y + a.y * b.x;
    return r;
}

template<int M>
__device__ __forceinline__ void intra_rot(v2f (&s)[16], float c, float sn) {
#pragma unroll
    for (int j = 0; j < 16; ++j)
        if ((j & M) == 0) {
            const int k = j | M;
            v2f v0 = s[j], v1 = s[k];
            s[j] = v0 * c - v1 * sn;
            s[k] = v0 * sn + v1 * c;
        }
}

// sign-carrying cross rotation: m = (+-s)*x, partner's m has opposite role sign:
// out = c*x - fetch(m)   (lane bit LM=0 -> sv=-s so out0 = c*x0 - s*x1;
//                         lane bit LM=1 -> partner m=-s*x0, out1 = c*x1 + s*x0)
template<class PF, int LM>
__device__ __forceinline__ void cross_rot(v2f (&s)[16], float c, float sn, int lane) {
    const float sv = (lane & LM) ? sn : -sn;
#pragma unroll
    for (int j = 0; j < 16; ++j) {
        v2f m = s[j] * sv;
        v2f p = PF::f(m);
        s[j] = s[j] * c - p;
    }
}

template<class PF>
__device__ __forceinline__ float cross_exp(const v2f (&s)[16]) {
    v2f acc = {0.f, 0.f};
#pragma unroll
    for (int j = 0; j < 16; ++j) {
        v2f p = PF::f(s[j]);
        acc += s[j] * p;
    }
    return acc.x + acc.y;
}

template<int M>
__device__ __forceinline__ float intra_exp(const v2f (&s)[16]) {
    v2f acc = {0.f, 0.f};
#pragma unroll
    for (int j = 0; j < 16; ++j)
        acc += s[j] * s[j ^ M];
    return acc.x + acc.y;
}

__global__ __launch_bounds__(64 * WPB) void qsim_kernel(
    const float* __restrict__ noise,     // (NBATCH, NQ)
    const float* __restrict__ qp,        // (NG, QD, NQ)
    float* __restrict__ out)             // (NBATCH, NG*NQ)
{
    const int wave = threadIdx.x >> 6;
    const int lane = threadIdx.x & 63;
    const int g    = blockIdx.x & 3;                  // block-uniform
    const int b    = (blockIdx.x >> 2) * WPB + wave;  // batch sample per wave

    // ---- per-sample noise angles ----
    float nc[NQ], ns[NQ];
#pragma unroll
    for (int q = 0; q < NQ; ++q) {
        float t = 0.5f * noise[b * NQ + q];
        __sincosf(t, &ns[q], &nc[q]);
    }

    // ---- weight angles: lane-parallel sincos once, readlane per layer ----
    float wcv, wsv;
    {
        const int widx = (lane < QD * NQ) ? lane : 0;
        float t = 0.5f * qp[g * (QD * NQ) + widx];
        __sincosf(t, &wsv, &wcv);
    }

    // ---- initial product state: RX(t)RY(t)|0> factor per qubit:
    //      bit=0 -> (c^2, -s^2)   bit=1 -> (cs, -cs)
    auto fac = [&](int q, int bit) -> v2f {
        float cc = nc[q], ss = ns[q];
        v2f r;
        if (bit) { r.x = cc * ss; r.y = -r.x; }
        else     { r.x = cc * cc; r.y = -ss * ss; }
        return r;
    };

    v2f h = {1.f, 0.f};
#pragma unroll
    for (int p = 4; p <= 9; ++p)
        h = cmul(h, fac(NQ - 1 - p, (lane >> (p - 4)) & 1));

    v2f s[16];
    {
        v2f t01[4], t23[4];
#pragma unroll
        for (int a = 0; a < 4; ++a) {
            t01[a] = cmul(fac(9, a & 1), fac(8, (a >> 1) & 1));
            t23[a] = cmul(fac(7, a & 1), fac(6, (a >> 1) & 1));
        }
        v2f pre[4];
#pragma unroll
        for (int a = 0; a < 4; ++a) pre[a] = cmul(h, t01[a]);
#pragma unroll
        for (int j = 0; j < 16; ++j) s[j] = cmul(pre[j & 3], t23[j >> 2]);
    }

    // ---- CZ-chain diagonal sign ----
    float czs[16];
#pragma unroll
    for (int j = 0; j < 16; ++j) {
        unsigned i = ((unsigned)lane << 4) | (unsigned)j;
        czs[j] = (__popc(i & (i >> 1)) & 1) ? -1.f : 1.f;
    }

    // ---- QD layers ----
#pragma unroll 1
    for (int l = 0; l < QD; ++l) {
        const int base = l * NQ;
        float c[NQ], sn[NQ];
#pragma unroll
        for (int q = 0; q < NQ; ++q) {
            c[q]  = rlane(wcv, base + q);
            sn[q] = rlane(wsv, base + q);
        }

        // wires 9..6: intra (reg bits 0..3)
        intra_rot<1>(s, c[9], sn[9]);
        intra_rot<2>(s, c[8], sn[8]);
        intra_rot<4>(s, c[7], sn[7]);
        intra_rot<8>(s, c[6], sn[6]);
        // wires 5..2: DPP cross (lane bits 0..3)
        cross_rot<FX1, 1>(s, c[5], sn[5], lane);
        cross_rot<FX2, 2>(s, c[4], sn[4], lane);
        cross_rot<FX4, 4>(s, c[3], sn[3], lane);
        cross_rot<FX8, 8>(s, c[2], sn[2], lane);
        // wires 1,0 (lane bits 4,5)
#if HAVE_SWAP
        tr_b5b3(s);                        // lane5 <-> reg3
        tr_b4b2(s);                        // lane4 <-> reg2
        intra_rot<8>(s, c[0], sn[0]);      // wire 0 now on reg bit 3
        intra_rot<4>(s, c[1], sn[1]);      // wire 1 now on reg bit 2
        tr_b4b2(s);
        tr_b5b3(s);
#else
        cross_rot<FX32,32>(s, c[0], sn[0], lane);
        cross_rot<FX16,16>(s, c[1], sn[1], lane);
#endif

        // CZ diagonal
#pragma unroll
        for (int j = 0; j < 16; ++j) s[j] *= czs[j];
    }

    // ---- expectations <X_q> ----
    float outval = 0.f;
    {
        float e9 = wave_reduce(intra_exp<1>(s));
        float e8 = wave_reduce(intra_exp<2>(s));
        float e7 = wave_reduce(intra_exp<4>(s));
        float e6 = wave_reduce(intra_exp<8>(s));
        float e5 = wave_reduce(cross_exp<FX1>(s));
        float e4 = wave_reduce(cross_exp<FX2>(s));
        float e3 = wave_reduce(cross_exp<FX4>(s));
        float e2 = wave_reduce(cross_exp<FX8>(s));
        float e0, e1;
#if HAVE_SWAP
        tr_b5b3(s);
        tr_b4b2(s);
        e0 = wave_reduce(intra_exp<8>(s));
        e1 = wave_reduce(intra_exp<4>(s));
#else
        e0 = wave_reduce(cross_exp<FX32>(s));
        e1 = wave_reduce(cross_exp<FX16>(s));
#endif
        outval = (lane == 0) ? e0 : outval;
        outval = (lane == 1) ? e1 : outval;
        outval = (lane == 2) ? e2 : outval;
        outval = (lane == 3) ? e3 : outval;
        outval = (lane == 4) ? e4 : outval;
        outval = (lane == 5) ? e5 : outval;
        outval = (lane == 6) ? e6 : outval;
        outval = (lane == 7) ? e7 : outval;
        outval = (lane == 8) ? e8 : outval;
        outval = (lane == 9) ? e9 : outval;
    }

    if (lane < NQ)
        out[b * (NG * NQ) + g * NQ + lane] = outval;
}

extern "C" void kernel_launch(void* const* d_in, const int* in_sizes, int n_in,
                              void* d_out, int out_size, void* d_ws, size_t ws_size,
                              hipStream_t stream) {
    const float* noise = (const float*)d_in[0];   // (1024, 10) float32
    const float* qp    = (const float*)d_in[1];   // (4, 6, 10) float32
    float* out = (float*)d_out;                   // (1024, 40) float32

    const int nblocks = (NBATCH * NG) / WPB;      // 1024 blocks x 4 waves
    qsim_kernel<<<nblocks, 64 * WPB, 0, stream>>>(noise, qp, out);
}